// Round 2
// baseline (4625.665 us; speedup 1.0000x reference)
//
#include <hip/hip_runtime.h>
#include <hip/hip_fp16.h>

#define N_VAR 256
#define M_CON 512
#define BATCH 64
#define SIGMA_C 1e-6f
#define RHO_C 0.1f
#define ALPHA_C 1.6f
#define NITERS 500

// ---------------------------------------------------------------------------
// K1: transpose A [512][256] -> At [256][512] per batch
// ---------------------------------------------------------------------------
__global__ __launch_bounds__(256) void k_transpose(const float* __restrict__ A,
                                                   float* __restrict__ At) {
  __shared__ float tile[32][33];
  int b = blockIdx.z;
  int n0 = blockIdx.x * 32;
  int m0 = blockIdx.y * 32;
  const float* Ab = A + (size_t)b * (M_CON * N_VAR);
  float* Atb = At + (size_t)b * (M_CON * N_VAR);
  int tx = threadIdx.x, ty = threadIdx.y;  // (32, 8)
#pragma unroll
  for (int j = 0; j < 32; j += 8)
    tile[ty + j][tx] = Ab[(size_t)(m0 + ty + j) * N_VAR + n0 + tx];
  __syncthreads();
#pragma unroll
  for (int j = 0; j < 32; j += 8)
    Atb[(size_t)(n0 + ty + j) * M_CON + m0 + tx] = tile[tx][ty + j];
}

// ---------------------------------------------------------------------------
// K2: batched NT GEMM  C[i][j] = alpha * sum_k X[i][k]*Y[j][k]  (+ diag)
// ---------------------------------------------------------------------------
__global__ __launch_bounds__(256) void k_ntgemm(
    const float* __restrict__ X, const float* __restrict__ Y,
    float* __restrict__ C, int I, int J, int K,
    long long bsX, long long bsY, long long bsC, float alpha,
    const float* __restrict__ diagv, int tilesJ) {
  int b = blockIdx.y;
  int ti = blockIdx.x / tilesJ, tj = blockIdx.x % tilesJ;
  int i0 = ti * 128, j0 = tj * 128;
  const float* Xb = X + (size_t)b * bsX;
  const float* Yb = Y + (size_t)b * bsY;
  float* Cb = C + (size_t)b * bsC;
  __shared__ float Xs[16][128];
  __shared__ float Ys[16][128];
  int tid = threadIdx.x;
  int tx = tid & 15, ty = tid >> 4;
  float acc[8][8];
#pragma unroll
  for (int r = 0; r < 8; ++r)
#pragma unroll
    for (int c = 0; c < 8; ++c) acc[r][c] = 0.0f;

  for (int kk = 0; kk < K; kk += 16) {
#pragma unroll
    for (int v = 0; v < 2; ++v) {
      int idx = v * 256 + tid;
      int row = idx >> 2;
      int k4 = (idx & 3) * 4;
      float4 gx = *(const float4*)(Xb + (size_t)(i0 + row) * K + kk + k4);
      Xs[k4 + 0][row] = gx.x; Xs[k4 + 1][row] = gx.y;
      Xs[k4 + 2][row] = gx.z; Xs[k4 + 3][row] = gx.w;
      float4 gy = *(const float4*)(Yb + (size_t)(j0 + row) * K + kk + k4);
      Ys[k4 + 0][row] = gy.x; Ys[k4 + 1][row] = gy.y;
      Ys[k4 + 2][row] = gy.z; Ys[k4 + 3][row] = gy.w;
    }
    __syncthreads();
#pragma unroll
    for (int k = 0; k < 16; ++k) {
      float xr[8], yr[8];
      *(float4*)&xr[0] = *(float4*)&Xs[k][ty * 8];
      *(float4*)&xr[4] = *(float4*)&Xs[k][ty * 8 + 4];
      *(float4*)&yr[0] = *(float4*)&Ys[k][tx * 8];
      *(float4*)&yr[4] = *(float4*)&Ys[k][tx * 8 + 4];
#pragma unroll
      for (int r = 0; r < 8; ++r)
#pragma unroll
        for (int c = 0; c < 8; ++c) acc[r][c] += xr[r] * yr[c];
    }
    __syncthreads();
  }
#pragma unroll
  for (int r = 0; r < 8; ++r) {
    int gi = i0 + ty * 8 + r;
#pragma unroll
    for (int c = 0; c < 8; ++c) {
      int gj = j0 + tx * 8 + c;
      float val = acc[r][c] * alpha;
      if (diagv != nullptr && gi == gj) val += diagv[(size_t)b * N_VAR + gi] + SIGMA_C;
      Cb[(size_t)gi * J + gj] = val;
    }
  }
}

// ---------------------------------------------------------------------------
// K3: BLOCKED Gauss-Jordan inversion, NB=8 (SPD, no pivoting; Schur
// complements of an SPD matrix stay SPD -> stable).
// ---------------------------------------------------------------------------
__global__ __launch_bounds__(512, 2) void k_invert(const float* __restrict__ Mk,
                                                   float* __restrict__ Mi) {
  int b = blockIdx.x;
  const float* src = Mk + (size_t)b * 65536;
  float* dst = Mi + (size_t)b * 65536;
  int t = threadIdx.x;
  int c = t & 255, rh = t >> 8;

  float a[128];
#pragma unroll
  for (int j = 0; j < 128; ++j) a[j] = src[(size_t)(rh * 128 + j) * 256 + c];

  __shared__ float colPan[256][8];     // old pivot-column panel [row][f]
  __shared__ float rowPan[2][8][260];  // raw pivot-row panel [buf][e][c]
  __shared__ float PiSh[64];           // 8x8 pivot-block inverse (flat)
  __shared__ float Rp[8][260];         // scaled pivot-row panel R' [e][c]

  int rh_s = __builtin_amdgcn_readfirstlane(rh);        // wave-uniform
  int cw_s = __builtin_amdgcn_readfirstlane((t >> 6) & 3);  // c-quadrant of wave

  if (rh == 0) {
#pragma unroll
    for (int j = 0; j < 8; ++j) rowPan[0][j][c] = a[j];  // block 0 rows
  }
  __syncthreads();

  for (int s = 0; s < 32; ++s) {
    int kb = s * 8;
    int cur = s & 1, nxt = cur ^ 1;
    int kh = kb >> 7, kj = kb & 127;          // pivot rows: half kh, offset kj
    int khn = (kb + 8) >> 7, kjn = (kb + 8) & 127;
    bool mycol = (c >= kb) && (c < kb + 8);   // per-lane

    // Phase A: threads owning pivot columns dump OLD values (2 waves active)
    if (cw_s == (kb >> 6)) {
      if (mycol) {
        int f = c - kb;
#pragma unroll
        for (int j = 0; j < 128; ++j) colPan[rh * 128 + j][f] = a[j];
      }
    }
    // Phase B (overlapped): wave 0 inverts the 8x8 pivot block via shuffles
    if (t < 64) {
      int e = t >> 3, f = t & 7;
      float p = rowPan[cur][e][kb + f];
#pragma unroll
      for (int k2 = 0; k2 < 8; ++k2) {
        float piv = __shfl(p, k2 * 8 + k2);
        float rv = __shfl(p, k2 * 8 + f);
        float cv = __shfl(p, e * 8 + k2);
        float pivinv = 1.0f / piv;
        float srv = rv * pivinv;
        float gen = p - cv * srv;
        p = gen;
        if (e == k2) p = srv;
        if (f == k2) p = -cv * pivinv;
        if (e == k2 && f == k2) p = pivinv;
      }
      PiSh[t] = p;
    }
    __syncthreads();  // B_mid: colPan + PiSh ready (rowPan[cur] since B_top)

    // Phase C: rp[e] = R'[e][c] in registers; pivot cols carry Pi columns
    float rpan[8];
#pragma unroll
    for (int f2 = 0; f2 < 8; ++f2) rpan[f2] = rowPan[cur][f2][c];
    float rp[8];
#pragma unroll
    for (int e = 0; e < 8; ++e) {
      float4 p0 = *(const float4*)&PiSh[e * 8];      // broadcast
      float4 p1 = *(const float4*)&PiSh[e * 8 + 4];
      rp[e] = p0.x * rpan[0] + p0.y * rpan[1] + p0.z * rpan[2] + p0.w * rpan[3] +
              p1.x * rpan[4] + p1.y * rpan[5] + p1.z * rpan[6] + p1.w * rpan[7];
    }
    if (cw_s == (kb >> 6)) {
      if (mycol) {
        int f = c - kb;
#pragma unroll
        for (int e = 0; e < 8; ++e) rp[e] = PiSh[e * 8 + f];
      }
    }
#pragma unroll
    for (int e = 0; e < 8; ++e) Rp[e][c] = rp[e];  // both rh: same value, benign

    // Phase D: rank-8 update of all 128 owned elements
    bool myhalfk = (rh_s == kh);
    bool stashw = (s != 31) && (rh_s == khn);
#pragma unroll
    for (int j = 0; j < 128; ++j) {
      float4 c0 = *(const float4*)&colPan[rh * 128 + j][0];  // broadcast
      float4 c1 = *(const float4*)&colPan[rh * 128 + j][4];
      float aold = a[j];
      float nv = aold -
                 (c0.x * rp[0] + c0.y * rp[1] + c0.z * rp[2] + c0.w * rp[3] +
                  c1.x * rp[4] + c1.y * rp[5] + c1.z * rp[6] + c1.w * rp[7]);
      if (mycol) nv -= aold;                       // pivot-col correction
      if (myhalfk && j >= kj && j < kj + 8)        // uniform scalar branch
        nv = Rp[j - kj][c];                        // pivot-row override
      a[j] = nv;
      if (stashw && j >= kjn && j < kjn + 8)       // uniform scalar branch
        rowPan[nxt][j - kjn][c] = nv;              // stash next pivot rows
    }
    __syncthreads();  // B_top: stash/colPan/Rp consumption complete
  }

#pragma unroll
  for (int j = 0; j < 128; ++j) dst[(size_t)(rh * 128 + j) * 256 + c] = a[j];
}

// ---------------------------------------------------------------------------
// K4a: h = Minv * q  (column access via symmetry)
// ---------------------------------------------------------------------------
__global__ __launch_bounds__(256) void k_matvec_h(const float* __restrict__ Mi,
                                                  const float* __restrict__ q,
                                                  float* __restrict__ h) {
  int b = blockIdx.x, t = threadIdx.x;
  __shared__ float qs[256];
  qs[t] = q[(size_t)b * 256 + t];
  __syncthreads();
  const float* Mb = Mi + (size_t)b * 65536;
  float acc = 0.0f;
  for (int k = 0; k < 256; ++k) acc += Mb[(size_t)k * 256 + t] * qs[k];
  h[(size_t)b * 256 + t] = acc;
}

// K4b: d = A * h  via At columns
__global__ __launch_bounds__(512) void k_matvec_d(const float* __restrict__ At,
                                                  const float* __restrict__ h,
                                                  float* __restrict__ d) {
  int b = blockIdx.x, t = threadIdx.x;
  __shared__ float hs[256];
  if (t < 256) hs[t] = h[(size_t)b * 256 + t];
  __syncthreads();
  const float* Ab = At + (size_t)b * 131072;
  float acc = 0.0f;
  for (int n = 0; n < 256; ++n) acc += Ab[(size_t)n * 512 + t] * hs[n];
  d[(size_t)b * 512 + t] = acc;
}

// ---------------------------------------------------------------------------
// K6: ADMM loop — round-8: WAVE-AUTONOMOUS, zero barriers in the loop.
// Round-7 (1 barrier + per-wave window polls) gave only -6%: the block-level
// convoy (all 8 waves join a barrier, then a 2-wave reduce, then store) kept
// the per-iter critical path at ~3400 cy while FMA issue is only ~512.
// Now each wave owns 16 rows end-to-end:
//   lane l polls the 8 packed (tag|w) u64 for columns [8l,8l+8) and feeds
//   them STRAIGHT from registers into acc[r] += G[r][8l+j]*w[j] (no LDS
//   staging of w, no redistribution). Partial transpose: 16 ds_write_b32 ->
//   4 ds_read_b128 (same-wave, lgkmcnt-ordered, pad 68 -> 2-way = free),
//   2-step quad shfl_xor; z/y/S update replicated over each row-quad; lane
//   q==0 stores the tagged w. Parity double-buffer + monotone tags unchanged
//   (a wave cannot advance 2 iters past any other: it needs their tags).
// Re-polls are exec-predicated per missing element to cap L3 poll traffic.
// ---------------------------------------------------------------------------
__global__ __launch_bounds__(512, 2) void k_admm4(
    const float* __restrict__ G, const float* __restrict__ dvec,
    const float* __restrict__ lv, const float* __restrict__ uv,
    unsigned long long* __restrict__ wtag, float* __restrict__ Sbuf) {
  int g = blockIdx.x;
  int b = (g & 7) + 8 * ((g >> 3) & 7);
  int s = g >> 6;
  int t = threadIdx.x;
  int l = t & 63, wv = t >> 6;

  __shared__ __align__(16) float part[8][16][68];  // per-wave partial panels

  // G fragment: rows [s*128+wv*16, +16), cols [8l, 8l+8)  (128 regs)
  const float* Gb = G + (size_t)b * 262144;
  int rbase = s * 128 + wv * 16;
  float Greg[128];
#pragma unroll
  for (int r = 0; r < 16; ++r) {
    const float* gp = Gb + (size_t)(rbase + r) * 512 + 8 * l;
    float4 a0 = *(const float4*)(gp);
    float4 a1 = *(const float4*)(gp + 4);
    Greg[r * 8 + 0] = a0.x; Greg[r * 8 + 1] = a0.y;
    Greg[r * 8 + 2] = a0.z; Greg[r * 8 + 3] = a0.w;
    Greg[r * 8 + 4] = a1.x; Greg[r * 8 + 5] = a1.y;
    Greg[r * 8 + 6] = a1.z; Greg[r * 8 + 7] = a1.w;
  }

  // Row this lane updates (4 lanes per row, replicated arithmetic)
  int r2 = l >> 2, q = l & 3;
  int row_u = rbase + r2;
  float lreg = lv[(size_t)b * 512 + row_u];
  float ureg = uv[(size_t)b * 512 + row_u];
  float dreg = dvec[(size_t)b * 512 + row_u];
  float zreg = 0.0f, yreg = 0.0f, Sreg = 0.0f;

  unsigned long long* wt0 = wtag + (size_t)b * 512;
  unsigned long long* wt1 = wtag + 32768 + (size_t)b * 512;

  float wj[8];
#pragma unroll
  for (int j = 0; j < 8; ++j) wj[j] = 0.0f;  // w_0 = 0

  for (int it = 0; it < NITERS; ++it) {
    if (it > 0) {
      unsigned long long* wp = (it & 1) ? wt1 : wt0;
      unsigned want = (unsigned)it;
      unsigned long long v[8];
#pragma unroll
      for (int j = 0; j < 8; ++j)
        v[j] = __hip_atomic_load(&wp[8 * l + j], __ATOMIC_RELAXED,
                                 __HIP_MEMORY_SCOPE_AGENT);
      for (;;) {
        bool ok = true;
#pragma unroll
        for (int j = 0; j < 8; ++j) ok &= ((unsigned)(v[j] >> 32) == want);
        if (__all(ok)) break;
        __builtin_amdgcn_s_sleep(1);
#pragma unroll
        for (int j = 0; j < 8; ++j)
          if ((unsigned)(v[j] >> 32) != want)
            v[j] = __hip_atomic_load(&wp[8 * l + j], __ATOMIC_RELAXED,
                                     __HIP_MEMORY_SCOPE_AGENT);
      }
#pragma unroll
      for (int j = 0; j < 8; ++j)
        wj[j] = __uint_as_float((unsigned)(v[j] & 0xffffffffu));
    }

    // 128 FMAs straight from registers
    float acc[16];
#pragma unroll
    for (int r = 0; r < 16; ++r) acc[r] = 0.0f;
#pragma unroll
    for (int j = 0; j < 8; ++j)
#pragma unroll
      for (int r = 0; r < 16; ++r) acc[r] += Greg[r * 8 + j] * wj[j];

    // transpose partials within the wave (same-wave LDS: no barrier)
#pragma unroll
    for (int r = 0; r < 16; ++r) part[wv][r][l] = acc[r];
    const float* pr = &part[wv][r2][q * 16];
    float4 s0 = *(const float4*)(pr);
    float4 s1 = *(const float4*)(pr + 4);
    float4 s2 = *(const float4*)(pr + 8);
    float4 s3 = *(const float4*)(pr + 12);
    float p16 = ((s0.x + s0.y) + (s0.z + s0.w)) +
                ((s1.x + s1.y) + (s1.z + s1.w)) +
                ((s2.x + s2.y) + (s2.z + s2.w)) +
                ((s3.x + s3.y) + (s3.z + s3.w));
    p16 += __shfl_xor(p16, 1);
    p16 += __shfl_xor(p16, 2);  // all 4 lanes of the quad: full row sum

    // z/y/S update (replicated across the quad; identical arithmetic)
    float w_old = RHO_C * zreg - yreg;
    Sreg = w_old - 0.6f * Sreg;
    float zt = p16 - dreg;
    float zh = ALPHA_C * zt + (1.0f - ALPHA_C) * zreg;
    float zc = zh + yreg * (1.0f / RHO_C);
    zc = fminf(fmaxf(zc, lreg), ureg);
    yreg += RHO_C * (zh - zc);
    zreg = zc;

    if (it < NITERS - 1) {
      float wn = RHO_C * zreg - yreg;
      if (q == 0) {
        unsigned long long pk =
            ((unsigned long long)(unsigned)(it + 1) << 32) |
            (unsigned long long)__float_as_uint(wn);
        unsigned long long* wp = ((it + 1) & 1) ? wt1 : wt0;
        __hip_atomic_store(&wp[row_u], pk, __ATOMIC_RELAXED,
                           __HIP_MEMORY_SCOPE_AGENT);
      }
    }
  }

  if (q == 0) Sbuf[(size_t)b * 512 + row_u] = Sreg;
}

// ---------------------------------------------------------------------------
// K7: epilogue  x = Minv * (alpha * A^T S - q)
// ---------------------------------------------------------------------------
__global__ __launch_bounds__(256) void k_final(
    const float* __restrict__ A, const float* __restrict__ q,
    const float* __restrict__ Mi, const float* __restrict__ Sbuf,
    float* __restrict__ xout) {
  int b = blockIdx.x, t = threadIdx.x;
  __shared__ float Ssh[512];
  __shared__ float uu[256];
  for (int i = t; i < 512; i += 256) Ssh[i] = Sbuf[(size_t)b * 512 + i];
  __syncthreads();
  const float* Ab = A + (size_t)b * 131072;
  float acc = 0.0f;
  for (int m = 0; m < 512; ++m) acc += Ab[(size_t)m * 256 + t] * Ssh[m];
  uu[t] = ALPHA_C * acc - q[(size_t)b * 256 + t];
  __syncthreads();
  const float* Mb = Mi + (size_t)b * 65536;
  float x = 0.0f;
  for (int kk = 0; kk < 256; ++kk) x += Mb[(size_t)kk * 256 + t] * uu[kk];
  xout[(size_t)b * 256 + t] = x;
}

// ---------------------------------------------------------------------------
extern "C" void kernel_launch(void* const* d_in, const int* in_sizes, int n_in,
                              void* d_out, int out_size, void* d_ws, size_t ws_size,
                              hipStream_t stream) {
  (void)in_sizes; (void)n_in; (void)out_size; (void)ws_size;
  const float* P = (const float*)d_in[0];
  const float* q = (const float*)d_in[1];
  const float* Av = (const float*)d_in[2];
  const float* lv = (const float*)d_in[3];
  const float* uv = (const float*)d_in[4];
  float* xout = (float*)d_out;

  float* ws = (float*)d_ws;
  float* At = ws;                       // 64*256*512; dies after k_matvec_d
  float* F  = ws;                       // alias of At; dies after ntgemm G
  float* Mi = ws + 8388608;             // 64*256*256
  float* Mk = ws + 12582912;            // dies after k_invert
  float* G  = ws + 12582912;            // 64*512*512 (over dead Mk)
  float* hv = ws + 29360128;            // 64*256
  float* dv = ws + 29376512;            // 64*512
  float* Sbuf = ws + 29409280;          // 64*512
  unsigned long long* wtag = (unsigned long long*)ws;  // overlays dead At/F

  k_transpose<<<dim3(8, 16, 64), dim3(32, 8), 0, stream>>>(Av, At);
  k_ntgemm<<<dim3(4, 64), 256, 0, stream>>>(At, At, Mk, 256, 256, 512,
                                            131072LL, 131072LL, 65536LL,
                                            RHO_C, P, 2);
  k_invert<<<64, 512, 0, stream>>>(Mk, Mi);
  k_matvec_h<<<64, 256, 0, stream>>>(Mi, q, hv);
  k_matvec_d<<<64, 512, 0, stream>>>(At, hv, dv);
  k_ntgemm<<<dim3(8, 64), 256, 0, stream>>>(Av, Mi, F, 512, 256, 256,
                                            131072LL, 65536LL, 131072LL,
                                            1.0f, nullptr, 2);
  k_ntgemm<<<dim3(16, 64), 256, 0, stream>>>(F, Av, G, 512, 512, 256,
                                             131072LL, 131072LL, 262144LL,
                                             1.0f, nullptr, 4);
  k_admm4<<<256, 512, 0, stream>>>(G, dv, lv, uv, wtag, Sbuf);
  k_final<<<64, 256, 0, stream>>>(Av, q, Mi, Sbuf, xout);
}

// Round 3
// 1614.646 us; speedup vs baseline: 2.8648x; 2.8648x over previous
//
#include <hip/hip_runtime.h>
#include <hip/hip_fp16.h>

#define N_VAR 256
#define M_CON 512
#define BATCH 64
#define SIGMA_C 1e-6f
#define RHO_C 0.1f
#define ALPHA_C 1.6f
#define NITERS 500

// ---------------------------------------------------------------------------
// K1: transpose A [512][256] -> At [256][512] per batch
// ---------------------------------------------------------------------------
__global__ __launch_bounds__(256) void k_transpose(const float* __restrict__ A,
                                                   float* __restrict__ At) {
  __shared__ float tile[32][33];
  int b = blockIdx.z;
  int n0 = blockIdx.x * 32;
  int m0 = blockIdx.y * 32;
  const float* Ab = A + (size_t)b * (M_CON * N_VAR);
  float* Atb = At + (size_t)b * (M_CON * N_VAR);
  int tx = threadIdx.x, ty = threadIdx.y;  // (32, 8)
#pragma unroll
  for (int j = 0; j < 32; j += 8)
    tile[ty + j][tx] = Ab[(size_t)(m0 + ty + j) * N_VAR + n0 + tx];
  __syncthreads();
#pragma unroll
  for (int j = 0; j < 32; j += 8)
    Atb[(size_t)(n0 + ty + j) * M_CON + m0 + tx] = tile[tx][ty + j];
}

// ---------------------------------------------------------------------------
// K2: batched NT GEMM  C[i][j] = alpha * sum_k X[i][k]*Y[j][k]  (+ diag)
// ---------------------------------------------------------------------------
__global__ __launch_bounds__(256) void k_ntgemm(
    const float* __restrict__ X, const float* __restrict__ Y,
    float* __restrict__ C, int I, int J, int K,
    long long bsX, long long bsY, long long bsC, float alpha,
    const float* __restrict__ diagv, int tilesJ) {
  int b = blockIdx.y;
  int ti = blockIdx.x / tilesJ, tj = blockIdx.x % tilesJ;
  int i0 = ti * 128, j0 = tj * 128;
  const float* Xb = X + (size_t)b * bsX;
  const float* Yb = Y + (size_t)b * bsY;
  float* Cb = C + (size_t)b * bsC;
  __shared__ float Xs[16][128];
  __shared__ float Ys[16][128];
  int tid = threadIdx.x;
  int tx = tid & 15, ty = tid >> 4;
  float acc[8][8];
#pragma unroll
  for (int r = 0; r < 8; ++r)
#pragma unroll
    for (int c = 0; c < 8; ++c) acc[r][c] = 0.0f;

  for (int kk = 0; kk < K; kk += 16) {
#pragma unroll
    for (int v = 0; v < 2; ++v) {
      int idx = v * 256 + tid;
      int row = idx >> 2;
      int k4 = (idx & 3) * 4;
      float4 gx = *(const float4*)(Xb + (size_t)(i0 + row) * K + kk + k4);
      Xs[k4 + 0][row] = gx.x; Xs[k4 + 1][row] = gx.y;
      Xs[k4 + 2][row] = gx.z; Xs[k4 + 3][row] = gx.w;
      float4 gy = *(const float4*)(Yb + (size_t)(j0 + row) * K + kk + k4);
      Ys[k4 + 0][row] = gy.x; Ys[k4 + 1][row] = gy.y;
      Ys[k4 + 2][row] = gy.z; Ys[k4 + 3][row] = gy.w;
    }
    __syncthreads();
#pragma unroll
    for (int k = 0; k < 16; ++k) {
      float xr[8], yr[8];
      *(float4*)&xr[0] = *(float4*)&Xs[k][ty * 8];
      *(float4*)&xr[4] = *(float4*)&Xs[k][ty * 8 + 4];
      *(float4*)&yr[0] = *(float4*)&Ys[k][tx * 8];
      *(float4*)&yr[4] = *(float4*)&Ys[k][tx * 8 + 4];
#pragma unroll
      for (int r = 0; r < 8; ++r)
#pragma unroll
        for (int c = 0; c < 8; ++c) acc[r][c] += xr[r] * yr[c];
    }
    __syncthreads();
  }
#pragma unroll
  for (int r = 0; r < 8; ++r) {
    int gi = i0 + ty * 8 + r;
#pragma unroll
    for (int c = 0; c < 8; ++c) {
      int gj = j0 + tx * 8 + c;
      float val = acc[r][c] * alpha;
      if (diagv != nullptr && gi == gj) val += diagv[(size_t)b * N_VAR + gi] + SIGMA_C;
      Cb[(size_t)gi * J + gj] = val;
    }
  }
}

// ---------------------------------------------------------------------------
// K3: BLOCKED Gauss-Jordan inversion, NB=8 (SPD, no pivoting; Schur
// complements of an SPD matrix stay SPD -> stable).
// ---------------------------------------------------------------------------
__global__ __launch_bounds__(512, 2) void k_invert(const float* __restrict__ Mk,
                                                   float* __restrict__ Mi) {
  int b = blockIdx.x;
  const float* src = Mk + (size_t)b * 65536;
  float* dst = Mi + (size_t)b * 65536;
  int t = threadIdx.x;
  int c = t & 255, rh = t >> 8;

  float a[128];
#pragma unroll
  for (int j = 0; j < 128; ++j) a[j] = src[(size_t)(rh * 128 + j) * 256 + c];

  __shared__ float colPan[256][8];     // old pivot-column panel [row][f]
  __shared__ float rowPan[2][8][260];  // raw pivot-row panel [buf][e][c]
  __shared__ float PiSh[64];           // 8x8 pivot-block inverse (flat)
  __shared__ float Rp[8][260];         // scaled pivot-row panel R' [e][c]

  int rh_s = __builtin_amdgcn_readfirstlane(rh);        // wave-uniform
  int cw_s = __builtin_amdgcn_readfirstlane((t >> 6) & 3);  // c-quadrant of wave

  if (rh == 0) {
#pragma unroll
    for (int j = 0; j < 8; ++j) rowPan[0][j][c] = a[j];  // block 0 rows
  }
  __syncthreads();

  for (int s = 0; s < 32; ++s) {
    int kb = s * 8;
    int cur = s & 1, nxt = cur ^ 1;
    int kh = kb >> 7, kj = kb & 127;          // pivot rows: half kh, offset kj
    int khn = (kb + 8) >> 7, kjn = (kb + 8) & 127;
    bool mycol = (c >= kb) && (c < kb + 8);   // per-lane

    // Phase A: threads owning pivot columns dump OLD values (2 waves active)
    if (cw_s == (kb >> 6)) {
      if (mycol) {
        int f = c - kb;
#pragma unroll
        for (int j = 0; j < 128; ++j) colPan[rh * 128 + j][f] = a[j];
      }
    }
    // Phase B (overlapped): wave 0 inverts the 8x8 pivot block via shuffles
    if (t < 64) {
      int e = t >> 3, f = t & 7;
      float p = rowPan[cur][e][kb + f];
#pragma unroll
      for (int k2 = 0; k2 < 8; ++k2) {
        float piv = __shfl(p, k2 * 8 + k2);
        float rv = __shfl(p, k2 * 8 + f);
        float cv = __shfl(p, e * 8 + k2);
        float pivinv = 1.0f / piv;
        float srv = rv * pivinv;
        float gen = p - cv * srv;
        p = gen;
        if (e == k2) p = srv;
        if (f == k2) p = -cv * pivinv;
        if (e == k2 && f == k2) p = pivinv;
      }
      PiSh[t] = p;
    }
    __syncthreads();  // B_mid: colPan + PiSh ready (rowPan[cur] since B_top)

    // Phase C: rp[e] = R'[e][c] in registers; pivot cols carry Pi columns
    float rpan[8];
#pragma unroll
    for (int f2 = 0; f2 < 8; ++f2) rpan[f2] = rowPan[cur][f2][c];
    float rp[8];
#pragma unroll
    for (int e = 0; e < 8; ++e) {
      float4 p0 = *(const float4*)&PiSh[e * 8];      // broadcast
      float4 p1 = *(const float4*)&PiSh[e * 8 + 4];
      rp[e] = p0.x * rpan[0] + p0.y * rpan[1] + p0.z * rpan[2] + p0.w * rpan[3] +
              p1.x * rpan[4] + p1.y * rpan[5] + p1.z * rpan[6] + p1.w * rpan[7];
    }
    if (cw_s == (kb >> 6)) {
      if (mycol) {
        int f = c - kb;
#pragma unroll
        for (int e = 0; e < 8; ++e) rp[e] = PiSh[e * 8 + f];
      }
    }
#pragma unroll
    for (int e = 0; e < 8; ++e) Rp[e][c] = rp[e];  // both rh: same value, benign

    // Phase D: rank-8 update of all 128 owned elements
    bool myhalfk = (rh_s == kh);
    bool stashw = (s != 31) && (rh_s == khn);
#pragma unroll
    for (int j = 0; j < 128; ++j) {
      float4 c0 = *(const float4*)&colPan[rh * 128 + j][0];  // broadcast
      float4 c1 = *(const float4*)&colPan[rh * 128 + j][4];
      float aold = a[j];
      float nv = aold -
                 (c0.x * rp[0] + c0.y * rp[1] + c0.z * rp[2] + c0.w * rp[3] +
                  c1.x * rp[4] + c1.y * rp[5] + c1.z * rp[6] + c1.w * rp[7]);
      if (mycol) nv -= aold;                       // pivot-col correction
      if (myhalfk && j >= kj && j < kj + 8)        // uniform scalar branch
        nv = Rp[j - kj][c];                        // pivot-row override
      a[j] = nv;
      if (stashw && j >= kjn && j < kjn + 8)       // uniform scalar branch
        rowPan[nxt][j - kjn][c] = nv;              // stash next pivot rows
    }
    __syncthreads();  // B_top: stash/colPan/Rp consumption complete
  }

#pragma unroll
  for (int j = 0; j < 128; ++j) dst[(size_t)(rh * 128 + j) * 256 + c] = a[j];
}

// ---------------------------------------------------------------------------
// K4a: h = Minv * q  (column access via symmetry)
// ---------------------------------------------------------------------------
__global__ __launch_bounds__(256) void k_matvec_h(const float* __restrict__ Mi,
                                                  const float* __restrict__ q,
                                                  float* __restrict__ h) {
  int b = blockIdx.x, t = threadIdx.x;
  __shared__ float qs[256];
  qs[t] = q[(size_t)b * 256 + t];
  __syncthreads();
  const float* Mb = Mi + (size_t)b * 65536;
  float acc = 0.0f;
  for (int k = 0; k < 256; ++k) acc += Mb[(size_t)k * 256 + t] * qs[k];
  h[(size_t)b * 256 + t] = acc;
}

// K4b: d = A * h  via At columns
__global__ __launch_bounds__(512) void k_matvec_d(const float* __restrict__ At,
                                                  const float* __restrict__ h,
                                                  float* __restrict__ d) {
  int b = blockIdx.x, t = threadIdx.x;
  __shared__ float hs[256];
  if (t < 256) hs[t] = h[(size_t)b * 256 + t];
  __syncthreads();
  const float* Ab = At + (size_t)b * 131072;
  float acc = 0.0f;
  for (int n = 0; n < 256; ++n) acc += Ab[(size_t)n * 512 + t] * hs[n];
  d[(size_t)b * 512 + t] = acc;
}

// ---------------------------------------------------------------------------
// K6: ADMM loop — round-9: round-1 structure + TRULY register-resident G.
// Diagnosis: rounds 0-2 all showed VGPR_Count 80-88, impossible with
// G0[64]+G1[64] live -> the compiler rematerialized the loop-invariant G
// loads INSIDE the iteration loop. 67 MB/iter of L2 re-reads at ~34 TB/s
// ~= 1.9 us/iter: the kernel was L2-BW-bound on G, which is why exchange
// restructuring (rounds 1-2) barely moved or hurt.
// Fix: asm-pin every G element after the load ("+v" makes the asm the
// value's definition -> cannot be re-loaded or sunk), and drop the
// min-waves launch_bounds hint that pushed the allocator to 80 regs.
// Also: latched sleep-free polling (each lane reloads only while its own
// tag is stale). Exchange protocol, barrier, update identical to round-1
// (proven at 713 us / absmax 0.0156).
// ---------------------------------------------------------------------------
__global__ __launch_bounds__(512) void k_admm4(
    const float* __restrict__ G, const float* __restrict__ dvec,
    const float* __restrict__ lv, const float* __restrict__ uv,
    unsigned long long* __restrict__ wtag, float* __restrict__ Sbuf) {
  int g = blockIdx.x;
  int b = (g & 7) + 8 * ((g >> 3) & 7);
  int s = g >> 6;
  int t = threadIdx.x;
  int l = t & 63, wv = t >> 6;
  int c0 = wv * 64;

  __shared__ __align__(16) float wbuf[8][64];  // wave-private w windows
  __shared__ float part[2][8][128];            // parity double-buffered partials

  const float* Gb = G + (size_t)b * 262144;
  const float* g0p = Gb + (size_t)(s * 128 + l) * 512 + c0;
  const float* g1p = Gb + (size_t)(s * 128 + 64 + l) * 512 + c0;
  float G0[64], G1[64];
#pragma unroll
  for (int j = 0; j < 16; ++j) {
    float4 v0 = *(const float4*)(g0p + 4 * j);
    G0[4 * j + 0] = v0.x; G0[4 * j + 1] = v0.y;
    G0[4 * j + 2] = v0.z; G0[4 * j + 3] = v0.w;
    float4 v1 = *(const float4*)(g1p + 4 * j);
    G1[4 * j + 0] = v1.x; G1[4 * j + 1] = v1.y;
    G1[4 * j + 2] = v1.z; G1[4 * j + 3] = v1.w;
  }
  // Pin G into VGPRs: the asm output becomes each value's definition, so the
  // compiler can neither rematerialize the loads inside the loop nor sink
  // them. ~160 VGPRs total -> fits 2 waves/SIMD without spilling.
#pragma unroll
  for (int j = 0; j < 64; ++j) {
    asm volatile("" : "+v"(G0[j]));
    asm volatile("" : "+v"(G1[j]));
  }

  float zreg = 0.0f, yreg = 0.0f, Sreg = 0.0f;
  float lreg = 0.0f, ureg = 0.0f, dreg = 0.0f;
  if (t < 128) {
    lreg = lv[(size_t)b * 512 + s * 128 + t];
    ureg = uv[(size_t)b * 512 + s * 128 + t];
    dreg = dvec[(size_t)b * 512 + s * 128 + t];
  }
  wbuf[wv][l] = 0.0f;  // w_0 = 0

  unsigned long long* wt0 = wtag + (size_t)b * 512;
  unsigned long long* wt1 = wtag + 32768 + (size_t)b * 512;
  const float4* wq4 = (const float4*)(wbuf[wv]);

  for (int it = 0; it < NITERS; ++it) {
    if (it > 0) {
      // latched poll of my wave's 64-element window: tag == it, buffer (it&1)
      unsigned long long* wp = (it & 1) ? wt1 : wt0;
      unsigned want = (unsigned)it;
      unsigned long long v = __hip_atomic_load(&wp[c0 + l], __ATOMIC_RELAXED,
                                               __HIP_MEMORY_SCOPE_AGENT);
      bool got = ((unsigned)(v >> 32) == want);
      while (!__all(got)) {
        if (!got) {
          unsigned long long v2 = __hip_atomic_load(
              &wp[c0 + l], __ATOMIC_RELAXED, __HIP_MEMORY_SCOPE_AGENT);
          if ((unsigned)(v2 >> 32) == want) { v = v2; got = true; }
        }
      }
      wbuf[wv][l] = __uint_as_float((unsigned)(v & 0xffffffffu));
      // same-wave ds_write -> ds_read: in-order, compiler inserts lgkmcnt
    }

    float r0a = 0.f, r0b = 0.f, r1a = 0.f, r1b = 0.f;
#pragma unroll
    for (int j = 0; j < 8; ++j) {
      float4 wa = wq4[2 * j];
      float4 wc = wq4[2 * j + 1];
      r0a += G0[8 * j + 0] * wa.x + G0[8 * j + 1] * wa.y +
             G0[8 * j + 2] * wa.z + G0[8 * j + 3] * wa.w;
      r1a += G1[8 * j + 0] * wa.x + G1[8 * j + 1] * wa.y +
             G1[8 * j + 2] * wa.z + G1[8 * j + 3] * wa.w;
      r0b += G0[8 * j + 4] * wc.x + G0[8 * j + 5] * wc.y +
             G0[8 * j + 6] * wc.z + G0[8 * j + 7] * wc.w;
      r1b += G1[8 * j + 4] * wc.x + G1[8 * j + 5] * wc.y +
             G1[8 * j + 6] * wc.z + G1[8 * j + 7] * wc.w;
    }
    int pp = it & 1;
    part[pp][wv][l] = r0a + r0b;
    part[pp][wv][64 + l] = r1a + r1b;
    __syncthreads();  // the ONLY barrier: partials of iter `it` visible

    if (t < 128) {
      float w_old = RHO_C * zreg - yreg;
      Sreg = w_old - 0.6f * Sreg;
      float p = part[pp][0][t] + part[pp][1][t] + part[pp][2][t] +
                part[pp][3][t] + part[pp][4][t] + part[pp][5][t] +
                part[pp][6][t] + part[pp][7][t];
      float zt = p - dreg;
      float zh = ALPHA_C * zt + (1.0f - ALPHA_C) * zreg;
      float zc = zh + yreg * (1.0f / RHO_C);
      zc = fminf(fmaxf(zc, lreg), ureg);
      yreg += RHO_C * (zh - zc);
      zreg = zc;
      if (it < NITERS - 1) {
        float wn = RHO_C * zreg - yreg;
        unsigned long long pk =
            ((unsigned long long)(unsigned)(it + 1) << 32) |
            (unsigned long long)__float_as_uint(wn);
        unsigned long long* wp = ((it + 1) & 1) ? wt1 : wt0;
        __hip_atomic_store(&wp[s * 128 + t], pk, __ATOMIC_RELAXED,
                           __HIP_MEMORY_SCOPE_AGENT);
      }
    }
  }

  if (t < 128) Sbuf[(size_t)b * 512 + s * 128 + t] = Sreg;
}

// ---------------------------------------------------------------------------
// K7: epilogue  x = Minv * (alpha * A^T S - q)
// ---------------------------------------------------------------------------
__global__ __launch_bounds__(256) void k_final(
    const float* __restrict__ A, const float* __restrict__ q,
    const float* __restrict__ Mi, const float* __restrict__ Sbuf,
    float* __restrict__ xout) {
  int b = blockIdx.x, t = threadIdx.x;
  __shared__ float Ssh[512];
  __shared__ float uu[256];
  for (int i = t; i < 512; i += 256) Ssh[i] = Sbuf[(size_t)b * 512 + i];
  __syncthreads();
  const float* Ab = A + (size_t)b * 131072;
  float acc = 0.0f;
  for (int m = 0; m < 512; ++m) acc += Ab[(size_t)m * 256 + t] * Ssh[m];
  uu[t] = ALPHA_C * acc - q[(size_t)b * 256 + t];
  __syncthreads();
  const float* Mb = Mi + (size_t)b * 65536;
  float x = 0.0f;
  for (int kk = 0; kk < 256; ++kk) x += Mb[(size_t)kk * 256 + t] * uu[kk];
  xout[(size_t)b * 256 + t] = x;
}

// ---------------------------------------------------------------------------
extern "C" void kernel_launch(void* const* d_in, const int* in_sizes, int n_in,
                              void* d_out, int out_size, void* d_ws, size_t ws_size,
                              hipStream_t stream) {
  (void)in_sizes; (void)n_in; (void)out_size; (void)ws_size;
  const float* P = (const float*)d_in[0];
  const float* q = (const float*)d_in[1];
  const float* Av = (const float*)d_in[2];
  const float* lv = (const float*)d_in[3];
  const float* uv = (const float*)d_in[4];
  float* xout = (float*)d_out;

  float* ws = (float*)d_ws;
  float* At = ws;                       // 64*256*512; dies after k_matvec_d
  float* F  = ws;                       // alias of At; dies after ntgemm G
  float* Mi = ws + 8388608;             // 64*256*256
  float* Mk = ws + 12582912;            // dies after k_invert
  float* G  = ws + 12582912;            // 64*512*512 (over dead Mk)
  float* hv = ws + 29360128;            // 64*256
  float* dv = ws + 29376512;            // 64*512
  float* Sbuf = ws + 29409280;          // 64*512
  unsigned long long* wtag = (unsigned long long*)ws;  // overlays dead At/F

  k_transpose<<<dim3(8, 16, 64), dim3(32, 8), 0, stream>>>(Av, At);
  k_ntgemm<<<dim3(4, 64), 256, 0, stream>>>(At, At, Mk, 256, 256, 512,
                                            131072LL, 131072LL, 65536LL,
                                            RHO_C, P, 2);
  k_invert<<<64, 512, 0, stream>>>(Mk, Mi);
  k_matvec_h<<<64, 256, 0, stream>>>(Mi, q, hv);
  k_matvec_d<<<64, 512, 0, stream>>>(At, hv, dv);
  k_ntgemm<<<dim3(8, 64), 256, 0, stream>>>(Av, Mi, F, 512, 256, 256,
                                            131072LL, 65536LL, 131072LL,
                                            1.0f, nullptr, 2);
  k_ntgemm<<<dim3(16, 64), 256, 0, stream>>>(F, Av, G, 512, 512, 256,
                                             131072LL, 131072LL, 262144LL,
                                             1.0f, nullptr, 4);
  k_admm4<<<256, 512, 0, stream>>>(G, dv, lv, uv, wtag, Sbuf);
  k_final<<<64, 256, 0, stream>>>(Av, q, Mi, Sbuf, xout);
}

// Round 4
// 1612.243 us; speedup vs baseline: 2.8691x; 1.0015x over previous
//
#include <hip/hip_runtime.h>
#include <hip/hip_fp16.h>

#define N_VAR 256
#define M_CON 512
#define BATCH 64
#define SIGMA_C 1e-6f
#define RHO_C 0.1f
#define ALPHA_C 1.6f
#define NITERS 500

// ---------------------------------------------------------------------------
// K1: transpose A [512][256] -> At [256][512] per batch
// ---------------------------------------------------------------------------
__global__ __launch_bounds__(256) void k_transpose(const float* __restrict__ A,
                                                   float* __restrict__ At) {
  __shared__ float tile[32][33];
  int b = blockIdx.z;
  int n0 = blockIdx.x * 32;
  int m0 = blockIdx.y * 32;
  const float* Ab = A + (size_t)b * (M_CON * N_VAR);
  float* Atb = At + (size_t)b * (M_CON * N_VAR);
  int tx = threadIdx.x, ty = threadIdx.y;  // (32, 8)
#pragma unroll
  for (int j = 0; j < 32; j += 8)
    tile[ty + j][tx] = Ab[(size_t)(m0 + ty + j) * N_VAR + n0 + tx];
  __syncthreads();
#pragma unroll
  for (int j = 0; j < 32; j += 8)
    Atb[(size_t)(n0 + ty + j) * M_CON + m0 + tx] = tile[tx][ty + j];
}

// ---------------------------------------------------------------------------
// K2: batched NT GEMM  C[i][j] = alpha * sum_k X[i][k]*Y[j][k]  (+ diag)
// ---------------------------------------------------------------------------
__global__ __launch_bounds__(256) void k_ntgemm(
    const float* __restrict__ X, const float* __restrict__ Y,
    float* __restrict__ C, int I, int J, int K,
    long long bsX, long long bsY, long long bsC, float alpha,
    const float* __restrict__ diagv, int tilesJ) {
  int b = blockIdx.y;
  int ti = blockIdx.x / tilesJ, tj = blockIdx.x % tilesJ;
  int i0 = ti * 128, j0 = tj * 128;
  const float* Xb = X + (size_t)b * bsX;
  const float* Yb = Y + (size_t)b * bsY;
  float* Cb = C + (size_t)b * bsC;
  __shared__ float Xs[16][128];
  __shared__ float Ys[16][128];
  int tid = threadIdx.x;
  int tx = tid & 15, ty = tid >> 4;
  float acc[8][8];
#pragma unroll
  for (int r = 0; r < 8; ++r)
#pragma unroll
    for (int c = 0; c < 8; ++c) acc[r][c] = 0.0f;

  for (int kk = 0; kk < K; kk += 16) {
#pragma unroll
    for (int v = 0; v < 2; ++v) {
      int idx = v * 256 + tid;
      int row = idx >> 2;
      int k4 = (idx & 3) * 4;
      float4 gx = *(const float4*)(Xb + (size_t)(i0 + row) * K + kk + k4);
      Xs[k4 + 0][row] = gx.x; Xs[k4 + 1][row] = gx.y;
      Xs[k4 + 2][row] = gx.z; Xs[k4 + 3][row] = gx.w;
      float4 gy = *(const float4*)(Yb + (size_t)(j0 + row) * K + kk + k4);
      Ys[k4 + 0][row] = gy.x; Ys[k4 + 1][row] = gy.y;
      Ys[k4 + 2][row] = gy.z; Ys[k4 + 3][row] = gy.w;
    }
    __syncthreads();
#pragma unroll
    for (int k = 0; k < 16; ++k) {
      float xr[8], yr[8];
      *(float4*)&xr[0] = *(float4*)&Xs[k][ty * 8];
      *(float4*)&xr[4] = *(float4*)&Xs[k][ty * 8 + 4];
      *(float4*)&yr[0] = *(float4*)&Ys[k][tx * 8];
      *(float4*)&yr[4] = *(float4*)&Ys[k][tx * 8 + 4];
#pragma unroll
      for (int r = 0; r < 8; ++r)
#pragma unroll
        for (int c = 0; c < 8; ++c) acc[r][c] += xr[r] * yr[c];
    }
    __syncthreads();
  }
#pragma unroll
  for (int r = 0; r < 8; ++r) {
    int gi = i0 + ty * 8 + r;
#pragma unroll
    for (int c = 0; c < 8; ++c) {
      int gj = j0 + tx * 8 + c;
      float val = acc[r][c] * alpha;
      if (diagv != nullptr && gi == gj) val += diagv[(size_t)b * N_VAR + gi] + SIGMA_C;
      Cb[(size_t)gi * J + gj] = val;
    }
  }
}

// ---------------------------------------------------------------------------
// K3: BLOCKED Gauss-Jordan inversion, NB=8 (SPD, no pivoting; Schur
// complements of an SPD matrix stay SPD -> stable).
// ---------------------------------------------------------------------------
__global__ __launch_bounds__(512, 2) void k_invert(const float* __restrict__ Mk,
                                                   float* __restrict__ Mi) {
  int b = blockIdx.x;
  const float* src = Mk + (size_t)b * 65536;
  float* dst = Mi + (size_t)b * 65536;
  int t = threadIdx.x;
  int c = t & 255, rh = t >> 8;

  float a[128];
#pragma unroll
  for (int j = 0; j < 128; ++j) a[j] = src[(size_t)(rh * 128 + j) * 256 + c];

  __shared__ float colPan[256][8];     // old pivot-column panel [row][f]
  __shared__ float rowPan[2][8][260];  // raw pivot-row panel [buf][e][c]
  __shared__ float PiSh[64];           // 8x8 pivot-block inverse (flat)
  __shared__ float Rp[8][260];         // scaled pivot-row panel R' [e][c]

  int rh_s = __builtin_amdgcn_readfirstlane(rh);        // wave-uniform
  int cw_s = __builtin_amdgcn_readfirstlane((t >> 6) & 3);  // c-quadrant of wave

  if (rh == 0) {
#pragma unroll
    for (int j = 0; j < 8; ++j) rowPan[0][j][c] = a[j];  // block 0 rows
  }
  __syncthreads();

  for (int s = 0; s < 32; ++s) {
    int kb = s * 8;
    int cur = s & 1, nxt = cur ^ 1;
    int kh = kb >> 7, kj = kb & 127;          // pivot rows: half kh, offset kj
    int khn = (kb + 8) >> 7, kjn = (kb + 8) & 127;
    bool mycol = (c >= kb) && (c < kb + 8);   // per-lane

    // Phase A: threads owning pivot columns dump OLD values (2 waves active)
    if (cw_s == (kb >> 6)) {
      if (mycol) {
        int f = c - kb;
#pragma unroll
        for (int j = 0; j < 128; ++j) colPan[rh * 128 + j][f] = a[j];
      }
    }
    // Phase B (overlapped): wave 0 inverts the 8x8 pivot block via shuffles
    if (t < 64) {
      int e = t >> 3, f = t & 7;
      float p = rowPan[cur][e][kb + f];
#pragma unroll
      for (int k2 = 0; k2 < 8; ++k2) {
        float piv = __shfl(p, k2 * 8 + k2);
        float rv = __shfl(p, k2 * 8 + f);
        float cv = __shfl(p, e * 8 + k2);
        float pivinv = 1.0f / piv;
        float srv = rv * pivinv;
        float gen = p - cv * srv;
        p = gen;
        if (e == k2) p = srv;
        if (f == k2) p = -cv * pivinv;
        if (e == k2 && f == k2) p = pivinv;
      }
      PiSh[t] = p;
    }
    __syncthreads();  // B_mid: colPan + PiSh ready (rowPan[cur] since B_top)

    // Phase C: rp[e] = R'[e][c] in registers; pivot cols carry Pi columns
    float rpan[8];
#pragma unroll
    for (int f2 = 0; f2 < 8; ++f2) rpan[f2] = rowPan[cur][f2][c];
    float rp[8];
#pragma unroll
    for (int e = 0; e < 8; ++e) {
      float4 p0 = *(const float4*)&PiSh[e * 8];      // broadcast
      float4 p1 = *(const float4*)&PiSh[e * 8 + 4];
      rp[e] = p0.x * rpan[0] + p0.y * rpan[1] + p0.z * rpan[2] + p0.w * rpan[3] +
              p1.x * rpan[4] + p1.y * rpan[5] + p1.z * rpan[6] + p1.w * rpan[7];
    }
    if (cw_s == (kb >> 6)) {
      if (mycol) {
        int f = c - kb;
#pragma unroll
        for (int e = 0; e < 8; ++e) rp[e] = PiSh[e * 8 + f];
      }
    }
#pragma unroll
    for (int e = 0; e < 8; ++e) Rp[e][c] = rp[e];  // both rh: same value, benign

    // Phase D: rank-8 update of all 128 owned elements
    bool myhalfk = (rh_s == kh);
    bool stashw = (s != 31) && (rh_s == khn);
#pragma unroll
    for (int j = 0; j < 128; ++j) {
      float4 c0 = *(const float4*)&colPan[rh * 128 + j][0];  // broadcast
      float4 c1 = *(const float4*)&colPan[rh * 128 + j][4];
      float aold = a[j];
      float nv = aold -
                 (c0.x * rp[0] + c0.y * rp[1] + c0.z * rp[2] + c0.w * rp[3] +
                  c1.x * rp[4] + c1.y * rp[5] + c1.z * rp[6] + c1.w * rp[7]);
      if (mycol) nv -= aold;                       // pivot-col correction
      if (myhalfk && j >= kj && j < kj + 8)        // uniform scalar branch
        nv = Rp[j - kj][c];                        // pivot-row override
      a[j] = nv;
      if (stashw && j >= kjn && j < kjn + 8)       // uniform scalar branch
        rowPan[nxt][j - kjn][c] = nv;              // stash next pivot rows
    }
    __syncthreads();  // B_top: stash/colPan/Rp consumption complete
  }

#pragma unroll
  for (int j = 0; j < 128; ++j) dst[(size_t)(rh * 128 + j) * 256 + c] = a[j];
}

// ---------------------------------------------------------------------------
// K4a: h = Minv * q  (column access via symmetry)
// ---------------------------------------------------------------------------
__global__ __launch_bounds__(256) void k_matvec_h(const float* __restrict__ Mi,
                                                  const float* __restrict__ q,
                                                  float* __restrict__ h) {
  int b = blockIdx.x, t = threadIdx.x;
  __shared__ float qs[256];
  qs[t] = q[(size_t)b * 256 + t];
  __syncthreads();
  const float* Mb = Mi + (size_t)b * 65536;
  float acc = 0.0f;
  for (int k = 0; k < 256; ++k) acc += Mb[(size_t)k * 256 + t] * qs[k];
  h[(size_t)b * 256 + t] = acc;
}

// K4b: d = A * h  via At columns
__global__ __launch_bounds__(512) void k_matvec_d(const float* __restrict__ At,
                                                  const float* __restrict__ h,
                                                  float* __restrict__ d) {
  int b = blockIdx.x, t = threadIdx.x;
  __shared__ float hs[256];
  if (t < 256) hs[t] = h[(size_t)b * 256 + t];
  __syncthreads();
  const float* Ab = At + (size_t)b * 131072;
  float acc = 0.0f;
  for (int n = 0; n < 256; ++n) acc += Ab[(size_t)n * 512 + t] * hs[n];
  d[(size_t)b * 512 + t] = acc;
}

// ---------------------------------------------------------------------------
// K6: ADMM loop — round-10: round-1 structure + G pinned in VGPRs, with the
// occupancy target pinned too.
// Round-3 post-mortem: asm-pin alone kept G values LIVE but the allocator
// (targeting ~6 waves/EU by heuristic) SPILLED them to scratch: VGPR_Count
// stayed 84 and the loop streamed 512 B/thread/iter from L2-cached scratch
// -> same ~1.5 us/iter L2-BW bound as rounds 0-2.
// Fix: amdgpu_waves_per_eu(2,2). The block is 8 waves = exactly 2 waves/SIMD
// at grid 256 = 1 block/CU, so occupancy target 2/EU is what we actually run;
// the allocator may then use up to ~256 VGPRs/wave and G0/G1 (128 regs) stay
// resident. At ~170 VGPRs, 2 blocks physically cannot co-reside on one CU
// (8 waves x 170 > 2048-reg pool / 2), so the 1-block-per-CU co-residency
// the spin-poll needs is hardware-guaranteed.
// VALIDATION BIT: VGPR_Count must jump 84 -> >=160.
// ---------------------------------------------------------------------------
__global__ __attribute__((amdgpu_waves_per_eu(2, 2))) __launch_bounds__(512)
void k_admm4(
    const float* __restrict__ G, const float* __restrict__ dvec,
    const float* __restrict__ lv, const float* __restrict__ uv,
    unsigned long long* __restrict__ wtag, float* __restrict__ Sbuf) {
  int g = blockIdx.x;
  int b = (g & 7) + 8 * ((g >> 3) & 7);
  int s = g >> 6;
  int t = threadIdx.x;
  int l = t & 63, wv = t >> 6;
  int c0 = wv * 64;

  __shared__ __align__(16) float wbuf[8][64];  // wave-private w windows
  __shared__ float part[2][8][128];            // parity double-buffered partials

  const float* Gb = G + (size_t)b * 262144;
  const float* g0p = Gb + (size_t)(s * 128 + l) * 512 + c0;
  const float* g1p = Gb + (size_t)(s * 128 + 64 + l) * 512 + c0;
  float G0[64], G1[64];
#pragma unroll
  for (int j = 0; j < 16; ++j) {
    float4 v0 = *(const float4*)(g0p + 4 * j);
    G0[4 * j + 0] = v0.x; G0[4 * j + 1] = v0.y;
    G0[4 * j + 2] = v0.z; G0[4 * j + 3] = v0.w;
    float4 v1 = *(const float4*)(g1p + 4 * j);
    G1[4 * j + 0] = v1.x; G1[4 * j + 1] = v1.y;
    G1[4 * j + 2] = v1.z; G1[4 * j + 3] = v1.w;
  }
  // Pin G into VGPRs: the asm output becomes each value's definition, so the
  // compiler can neither rematerialize the loads inside the loop nor sink
  // them. With waves_per_eu(2,2) the allocator has the budget to keep them.
#pragma unroll
  for (int j = 0; j < 64; ++j) {
    asm volatile("" : "+v"(G0[j]));
    asm volatile("" : "+v"(G1[j]));
  }

  float zreg = 0.0f, yreg = 0.0f, Sreg = 0.0f;
  float lreg = 0.0f, ureg = 0.0f, dreg = 0.0f;
  if (t < 128) {
    lreg = lv[(size_t)b * 512 + s * 128 + t];
    ureg = uv[(size_t)b * 512 + s * 128 + t];
    dreg = dvec[(size_t)b * 512 + s * 128 + t];
  }
  wbuf[wv][l] = 0.0f;  // w_0 = 0

  unsigned long long* wt0 = wtag + (size_t)b * 512;
  unsigned long long* wt1 = wtag + 32768 + (size_t)b * 512;
  const float4* wq4 = (const float4*)(wbuf[wv]);

  for (int it = 0; it < NITERS; ++it) {
    if (it > 0) {
      // latched poll of my wave's 64-element window: tag == it, buffer (it&1)
      unsigned long long* wp = (it & 1) ? wt1 : wt0;
      unsigned want = (unsigned)it;
      unsigned long long v = __hip_atomic_load(&wp[c0 + l], __ATOMIC_RELAXED,
                                               __HIP_MEMORY_SCOPE_AGENT);
      bool got = ((unsigned)(v >> 32) == want);
      while (!__all(got)) {
        if (!got) {
          unsigned long long v2 = __hip_atomic_load(
              &wp[c0 + l], __ATOMIC_RELAXED, __HIP_MEMORY_SCOPE_AGENT);
          if ((unsigned)(v2 >> 32) == want) { v = v2; got = true; }
        }
      }
      wbuf[wv][l] = __uint_as_float((unsigned)(v & 0xffffffffu));
      // same-wave ds_write -> ds_read: in-order, compiler inserts lgkmcnt
    }

    float r0a = 0.f, r0b = 0.f, r1a = 0.f, r1b = 0.f;
#pragma unroll
    for (int j = 0; j < 8; ++j) {
      float4 wa = wq4[2 * j];
      float4 wc = wq4[2 * j + 1];
      r0a += G0[8 * j + 0] * wa.x + G0[8 * j + 1] * wa.y +
             G0[8 * j + 2] * wa.z + G0[8 * j + 3] * wa.w;
      r1a += G1[8 * j + 0] * wa.x + G1[8 * j + 1] * wa.y +
             G1[8 * j + 2] * wa.z + G1[8 * j + 3] * wa.w;
      r0b += G0[8 * j + 4] * wc.x + G0[8 * j + 5] * wc.y +
             G0[8 * j + 6] * wc.z + G0[8 * j + 7] * wc.w;
      r1b += G1[8 * j + 4] * wc.x + G1[8 * j + 5] * wc.y +
             G1[8 * j + 6] * wc.z + G1[8 * j + 7] * wc.w;
    }
    int pp = it & 1;
    part[pp][wv][l] = r0a + r0b;
    part[pp][wv][64 + l] = r1a + r1b;
    __syncthreads();  // the ONLY barrier: partials of iter `it` visible

    if (t < 128) {
      float w_old = RHO_C * zreg - yreg;
      Sreg = w_old - 0.6f * Sreg;
      float p = part[pp][0][t] + part[pp][1][t] + part[pp][2][t] +
                part[pp][3][t] + part[pp][4][t] + part[pp][5][t] +
                part[pp][6][t] + part[pp][7][t];
      float zt = p - dreg;
      float zh = ALPHA_C * zt + (1.0f - ALPHA_C) * zreg;
      float zc = zh + yreg * (1.0f / RHO_C);
      zc = fminf(fmaxf(zc, lreg), ureg);
      yreg += RHO_C * (zh - zc);
      zreg = zc;
      if (it < NITERS - 1) {
        float wn = RHO_C * zreg - yreg;
        unsigned long long pk =
            ((unsigned long long)(unsigned)(it + 1) << 32) |
            (unsigned long long)__float_as_uint(wn);
        unsigned long long* wp = ((it + 1) & 1) ? wt1 : wt0;
        __hip_atomic_store(&wp[s * 128 + t], pk, __ATOMIC_RELAXED,
                           __HIP_MEMORY_SCOPE_AGENT);
      }
    }
  }

  if (t < 128) Sbuf[(size_t)b * 512 + s * 128 + t] = Sreg;
}

// ---------------------------------------------------------------------------
// K7: epilogue  x = Minv * (alpha * A^T S - q)
// ---------------------------------------------------------------------------
__global__ __launch_bounds__(256) void k_final(
    const float* __restrict__ A, const float* __restrict__ q,
    const float* __restrict__ Mi, const float* __restrict__ Sbuf,
    float* __restrict__ xout) {
  int b = blockIdx.x, t = threadIdx.x;
  __shared__ float Ssh[512];
  __shared__ float uu[256];
  for (int i = t; i < 512; i += 256) Ssh[i] = Sbuf[(size_t)b * 512 + i];
  __syncthreads();
  const float* Ab = A + (size_t)b * 131072;
  float acc = 0.0f;
  for (int m = 0; m < 512; ++m) acc += Ab[(size_t)m * 256 + t] * Ssh[m];
  uu[t] = ALPHA_C * acc - q[(size_t)b * 256 + t];
  __syncthreads();
  const float* Mb = Mi + (size_t)b * 65536;
  float x = 0.0f;
  for (int kk = 0; kk < 256; ++kk) x += Mb[(size_t)kk * 256 + t] * uu[kk];
  xout[(size_t)b * 256 + t] = x;
}

// ---------------------------------------------------------------------------
extern "C" void kernel_launch(void* const* d_in, const int* in_sizes, int n_in,
                              void* d_out, int out_size, void* d_ws, size_t ws_size,
                              hipStream_t stream) {
  (void)in_sizes; (void)n_in; (void)out_size; (void)ws_size;
  const float* P = (const float*)d_in[0];
  const float* q = (const float*)d_in[1];
  const float* Av = (const float*)d_in[2];
  const float* lv = (const float*)d_in[3];
  const float* uv = (const float*)d_in[4];
  float* xout = (float*)d_out;

  float* ws = (float*)d_ws;
  float* At = ws;                       // 64*256*512; dies after k_matvec_d
  float* F  = ws;                       // alias of At; dies after ntgemm G
  float* Mi = ws + 8388608;             // 64*256*256
  float* Mk = ws + 12582912;            // dies after k_invert
  float* G  = ws + 12582912;            // 64*512*512 (over dead Mk)
  float* hv = ws + 29360128;            // 64*256
  float* dv = ws + 29376512;            // 64*512
  float* Sbuf = ws + 29409280;          // 64*512
  unsigned long long* wtag = (unsigned long long*)ws;  // overlays dead At/F

  k_transpose<<<dim3(8, 16, 64), dim3(32, 8), 0, stream>>>(Av, At);
  k_ntgemm<<<dim3(4, 64), 256, 0, stream>>>(At, At, Mk, 256, 256, 512,
                                            131072LL, 131072LL, 65536LL,
                                            RHO_C, P, 2);
  k_invert<<<64, 512, 0, stream>>>(Mk, Mi);
  k_matvec_h<<<64, 256, 0, stream>>>(Mi, q, hv);
  k_matvec_d<<<64, 512, 0, stream>>>(At, hv, dv);
  k_ntgemm<<<dim3(8, 64), 256, 0, stream>>>(Av, Mi, F, 512, 256, 256,
                                            131072LL, 65536LL, 131072LL,
                                            1.0f, nullptr, 2);
  k_ntgemm<<<dim3(16, 64), 256, 0, stream>>>(F, Av, G, 512, 512, 256,
                                             131072LL, 131072LL, 262144LL,
                                             1.0f, nullptr, 4);
  k_admm4<<<256, 512, 0, stream>>>(G, dv, lv, uv, wtag, Sbuf);
  k_final<<<64, 256, 0, stream>>>(Av, q, Mi, Sbuf, xout);
}